// Round 3
// baseline (375.945 us; speedup 1.0000x reference)
//
#include <hip/hip_runtime.h>
#include <hip/hip_bf16.h>
#include <float.h>
#include <math.h>

#define KEY_DIM   512
#define VALUE_DIM 128
#define CAPACITY  500000   // divisible by 4
#define NRET      16
#define NBLK2     1024     // blocks for the similarity kernel
#define ROWS      4        // rows per wave-iteration

__device__ __forceinline__ float wave_sum(float x) {
#pragma unroll
    for (int s = 32; s > 0; s >>= 1) x += __shfl_xor(x, s);
    return x;
}

// ---------------- Kernel 1a/1b: y[r] = act(dot(W[r,:], x) + b[r]) ----------
template <bool SILU>
__global__ __launch_bounds__(256) void matvec512(
        const float* __restrict__ W, const float* __restrict__ x,
        const float* __restrict__ b, float* __restrict__ y) {
    const int wid  = threadIdx.x >> 6;
    const int lane = threadIdx.x & 63;
    const int r = blockIdx.x * 4 + wid;          // 0..511

    const float4* Wr = (const float4*)(W + (size_t)r * KEY_DIM);
    const float4* xv = (const float4*)x;

    float4 w0 = Wr[lane], w1 = Wr[lane + 64];
    float4 x0 = xv[lane], x1 = xv[lane + 64];

    float dot = w0.x * x0.x + w0.y * x0.y + w0.z * x0.z + w0.w * x0.w
              + w1.x * x1.x + w1.y * x1.y + w1.z * x1.z + w1.w * x1.w;
    dot = wave_sum(dot);

    if (lane == 0) {
        float v = dot + b[r];
        if (SILU) v = v / (1.0f + expf(-v));     // silu = x*sigmoid(x)
        y[r] = v;
    }
}

// ---------------- Kernel 1c: LayerNorm + l2-normalize -> qn[512] -----------
__global__ __launch_bounds__(512) void ln_l2norm(
        const float* __restrict__ h, const float* __restrict__ gamma,
        const float* __restrict__ beta, float* __restrict__ qn) {
    __shared__ float s1[8], s2[8];
    const int t = threadIdx.x;                   // 512 threads = 8 waves
    const int wid = t >> 6, lane = t & 63;

    float x = h[t];
    float a = x, bb = x * x;
#pragma unroll
    for (int s = 32; s > 0; s >>= 1) { a += __shfl_xor(a, s); bb += __shfl_xor(bb, s); }
    if (lane == 0) { s1[wid] = a; s2[wid] = bb; }
    __syncthreads();

    float suma = 0.f, sumb = 0.f;
#pragma unroll
    for (int i = 0; i < 8; ++i) { suma += s1[i]; sumb += s2[i]; }
    float mu  = suma * (1.0f / KEY_DIM);
    float var = sumb * (1.0f / KEY_DIM) - mu * mu;      // biased, like torch LN
    float ln  = (x - mu) / sqrtf(var + 1e-5f) * gamma[t] + beta[t];

    float c = wave_sum(ln * ln);
    __syncthreads();
    if (lane == 0) s1[wid] = c;
    __syncthreads();
    float ss = 0.f;
#pragma unroll
    for (int i = 0; i < 8; ++i) ss += s1[i];
    float n = fmaxf(sqrtf(ss), 1e-12f);
    qn[t] = ln / n;
}

// ---------------- Kernel 2: cosine sim + per-block top-16 ------------------
// Register double-buffered pipeline: tile t+1's 8 loads are issued BEFORE the
// reduction of tile t, so 8 KB/wave stays in flight across the compute phase.
// Quarter-packed butterfly: stages {32,16} per row, pack 4 rows into lane
// quarters, stages {8,4,2,1} once, one rsqrt/div, 4 broadcasts.

__device__ __forceinline__ void load_tile(const float* __restrict__ keys,
                                          int base, int lane,
                                          float4 (&a)[ROWS], float4 (&b)[ROWS]) {
#pragma unroll
    for (int j = 0; j < ROWS; ++j) {
        const float4* kp = (const float4*)(keys + (size_t)(base + j) * KEY_DIM);
        a[j] = kp[lane];
        b[j] = kp[lane + 64];
    }
}

__device__ __forceinline__ void process_tile(const float4 (&a)[ROWS], const float4 (&b)[ROWS],
                                             float4 q0, float4 q1, int base, int lane,
                                             float (&v)[16], int (&id)[16]) {
    float dot[ROWS], ss[ROWS];
#pragma unroll
    for (int j = 0; j < ROWS; ++j) {
        dot[j] = a[j].x * q0.x + a[j].y * q0.y + a[j].z * q0.z + a[j].w * q0.w
               + b[j].x * q1.x + b[j].y * q1.y + b[j].z * q1.z + b[j].w * q1.w;
        ss[j]  = a[j].x * a[j].x + a[j].y * a[j].y + a[j].z * a[j].z + a[j].w * a[j].w
               + b[j].x * b[j].x + b[j].y * b[j].y + b[j].z * b[j].z + b[j].w * b[j].w;
    }
    // stages 32,16 for each row: lane i -> sum over {j : j == i (mod 16)}
#pragma unroll
    for (int s = 32; s >= 16; s >>= 1) {
#pragma unroll
        for (int j = 0; j < ROWS; ++j) {
            dot[j] += __shfl_xor(dot[j], s);
            ss[j]  += __shfl_xor(ss[j], s);
        }
    }
    // pack: lane quarter q takes row q's partials
    const int qid = lane >> 4;
    float pd = (qid == 0) ? dot[0] : (qid == 1) ? dot[1] : (qid == 2) ? dot[2] : dot[3];
    float ps = (qid == 0) ? ss[0]  : (qid == 1) ? ss[1]  : (qid == 2) ? ss[2]  : ss[3];
#pragma unroll
    for (int s = 8; s > 0; s >>= 1) {
        pd += __shfl_xor(pd, s);
        ps += __shfl_xor(ps, s);
    }
    float simp = pd / fmaxf(sqrtf(ps), 1e-12f);   // lane in quarter q: sim of row q

    // broadcast each quarter's sim -> wave-uniform, then uniform insert
#pragma unroll
    for (int j = 0; j < ROWS; ++j) {
        float sim = __shfl(simp, j << 4);
        if (sim > v[15]) {                        // wave-uniform branch
            float cv = sim; int ci = base + j;
#pragma unroll
            for (int jj = 0; jj < 16; ++jj) {
                if (cv > v[jj]) {
                    float tv = v[jj]; int ti = id[jj];
                    v[jj] = cv; id[jj] = ci; cv = tv; ci = ti;
                }
            }
        }
    }
}

__global__ __launch_bounds__(256) void sim_topk(
        const float* __restrict__ keys, const float* __restrict__ qn,
        float* __restrict__ cand_v, int* __restrict__ cand_i) {
    const int wid  = threadIdx.x >> 6;
    const int lane = threadIdx.x & 63;
    const int gw   = blockIdx.x * 4 + wid;        // global wave id
    const int STRIDE = NBLK2 * 4 * ROWS;          // rows per grid-iteration

    const float4* q = (const float4*)qn;
    float4 q0 = q[lane], q1 = q[lane + 64];

    float v[16]; int id[16];
#pragma unroll
    for (int j = 0; j < 16; ++j) { v[j] = -FLT_MAX; id[j] = 0x7fffffff; }

    float4 A0[ROWS], B0[ROWS];                    // buffer A
    float4 A1[ROWS], B1[ROWS];                    // buffer B

    int base = gw * ROWS;                         // < 16384 < CAPACITY always
    load_tile(keys, base, lane, A0, B0);

    for (;;) {
        // ---- A in flight/ready; prefetch into B, process A ----
        int nbase = base + STRIDE;
        bool more = nbase < CAPACITY;
        if (more) load_tile(keys, nbase, lane, A1, B1);
        process_tile(A0, B0, q0, q1, base, lane, v, id);
        if (!more) break;
        base = nbase;

        // ---- B ready; prefetch into A, process B ----
        nbase = base + STRIDE;
        more = nbase < CAPACITY;
        if (more) load_tile(keys, nbase, lane, A0, B0);
        process_tile(A1, B1, q0, q1, base, lane, v, id);
        if (!more) break;
        base = nbase;
    }

    // merge 4 waves' top-16 -> block top-16
    __shared__ float bv[64];
    __shared__ int   bi[64];
    if (lane == 0) {
#pragma unroll
        for (int j = 0; j < 16; ++j) { bv[wid * 16 + j] = v[j]; bi[wid * 16 + j] = id[j]; }
    }
    __syncthreads();
    if (wid == 0) {
        float lv = bv[lane]; int li = bi[lane];
        for (int rr = 0; rr < NRET; ++rr) {
            float mv = lv; int mi = li;
#pragma unroll
            for (int s = 32; s > 0; s >>= 1) {
                float ov = __shfl_xor(mv, s); int oi = __shfl_xor(mi, s);
                if (ov > mv || (ov == mv && oi < mi)) { mv = ov; mi = oi; }
            }
            if (lane == 0) {
                cand_v[blockIdx.x * NRET + rr] = mv;
                cand_i[blockIdx.x * NRET + rr] = mi;
            }
            if (lv == mv && li == mi) { lv = -FLT_MAX; li = 0x7fffffff; }  // pop winner
        }
    }
}

// ---------------- Kernel 3: global top-16 + softmax + gather ---------------
__global__ __launch_bounds__(256) void merge_out(
        const float* __restrict__ cand_v, const int* __restrict__ cand_i,
        const float* __restrict__ values, float* __restrict__ out) {
    const int tid  = threadIdx.x;
    const int wid  = tid >> 6;
    const int lane = tid & 63;
    const int M = NBLK2 * NRET;                  // 16384

    float v[16]; int id[16];
#pragma unroll
    for (int j = 0; j < 16; ++j) { v[j] = -FLT_MAX; id[j] = 0x7fffffff; }

    for (int c = tid; c < M; c += 256) {         // 64 iterations
        float cv = cand_v[c]; int ci = cand_i[c];
        if (cv > v[15]) {                        // per-lane (divergent) insert
#pragma unroll
            for (int j = 0; j < 16; ++j) {
                if (cv > v[j]) {
                    float tv = v[j]; int ti = id[j];
                    v[j] = cv; id[j] = ci; cv = tv; ci = ti;
                }
            }
        }
    }

    // per-wave argmax-pop of 16 winners -> LDS
    __shared__ float sv[64];
    __shared__ int   si[64];
    for (int rr = 0; rr < NRET; ++rr) {
        float mv = v[0]; int mi = id[0];
#pragma unroll
        for (int s = 32; s > 0; s >>= 1) {
            float ov = __shfl_xor(mv, s); int oi = __shfl_xor(mi, s);
            if (ov > mv || (ov == mv && oi < mi)) { mv = ov; mi = oi; }
        }
        if (v[0] == mv && id[0] == mi) {         // unique winner (unique indices)
#pragma unroll
            for (int j = 0; j < 15; ++j) { v[j] = v[j + 1]; id[j] = id[j + 1]; }
            v[15] = -FLT_MAX; id[15] = 0x7fffffff;
        }
        if (lane == 0) { sv[wid * 16 + rr] = mv; si[wid * 16 + rr] = mi; }
    }
    __syncthreads();

    if (wid == 0) {
        float lv = sv[lane]; int li = si[lane];
        float sel_v = -FLT_MAX; int sel_i = 0;
        for (int rr = 0; rr < NRET; ++rr) {
            float mv = lv; int mi = li;
#pragma unroll
            for (int s = 32; s > 0; s >>= 1) {
                float ov = __shfl_xor(mv, s); int oi = __shfl_xor(mi, s);
                if (ov > mv || (ov == mv && oi < mi)) { mv = ov; mi = oi; }
            }
            if (lv == mv && li == mi) { lv = -FLT_MAX; li = 0x7fffffff; }
            if (lane == rr) { sel_v = mv; sel_i = mi; }
        }

        // softmax over the 16 (lane 0 holds the max: rounds are descending)
        float m0 = __shfl(sel_v, 0);
        float e = (lane < NRET) ? expf(sel_v - m0) : 0.0f;
        float denom = wave_sum(e);

        float acc0 = 0.f, acc1 = 0.f;
        for (int rr = 0; rr < NRET; ++rr) {
            float ar = __shfl(e, rr) / denom;
            int   ir = __shfl(sel_i, rr);
            const float* vr = values + (size_t)ir * VALUE_DIM;
            acc0 += ar * vr[lane];
            acc1 += ar * vr[lane + 64];
        }
        out[lane]      = acc0;
        out[lane + 64] = acc1;
    }
}

extern "C" void kernel_launch(void* const* d_in, const int* in_sizes, int n_in,
                              void* d_out, int out_size, void* d_ws, size_t ws_size,
                              hipStream_t stream) {
    const float* query  = (const float*)d_in[0];
    const float* W1     = (const float*)d_in[1];
    const float* b1     = (const float*)d_in[2];
    const float* W2     = (const float*)d_in[3];
    const float* b2     = (const float*)d_in[4];
    const float* gamma  = (const float*)d_in[5];
    const float* beta   = (const float*)d_in[6];
    const float* keys   = (const float*)d_in[7];
    const float* values = (const float*)d_in[8];
    float* out = (float*)d_out;

    float* ws = (float*)d_ws;
    float* h1     = ws;                  // 512
    float* h2     = ws + 512;            // 512
    float* qn     = ws + 1024;           // 512
    float* cand_v = ws + 2048;           // NBLK2*16 floats
    int*   cand_i = (int*)(ws + 2048 + NBLK2 * NRET);

    matvec512<true ><<<128, 256, 0, stream>>>(W1, query, b1, h1);
    matvec512<false><<<128, 256, 0, stream>>>(W2, h1, b2, h2);
    ln_l2norm<<<1, 512, 0, stream>>>(h2, gamma, beta, qn);
    sim_topk<<<NBLK2, 256, 0, stream>>>(keys, qn, cand_v, cand_i);
    merge_out<<<1, 256, 0, stream>>>(cand_v, cand_i, values, out);
}

// Round 4
// 371.533 us; speedup vs baseline: 1.0119x; 1.0119x over previous
//
#include <hip/hip_runtime.h>
#include <hip/hip_bf16.h>
#include <float.h>
#include <math.h>

#define KEY_DIM   512
#define VALUE_DIM 128
#define CAPACITY  500000
#define NRET      16
#define NBLK2     1024       // blocks for the similarity kernel
#define NWAVES    (NBLK2*4)  // 4096 waves
#define TSTRIDE   (NWAVES*2) // 8192 rows per sweep (2 rows/tile)
#define NTILES    61         // uniform tiles/wave: 61*8192 = 499712 rows
#define TAILROWS  (CAPACITY - NTILES*TSTRIDE)   // 288 -> waves 0..143

__device__ __forceinline__ float wave_sum(float x) {
#pragma unroll
    for (int s = 32; s > 0; s >>= 1) x += __shfl_xor(x, s);
    return x;
}

// ---------------- Kernel 1a/1b: y[r] = act(dot(W[r,:], x) + b[r]) ----------
template <bool SILU>
__global__ __launch_bounds__(256) void matvec512(
        const float* __restrict__ W, const float* __restrict__ x,
        const float* __restrict__ b, float* __restrict__ y) {
    const int wid  = threadIdx.x >> 6;
    const int lane = threadIdx.x & 63;
    const int r = blockIdx.x * 4 + wid;          // 0..511

    const float4* Wr = (const float4*)(W + (size_t)r * KEY_DIM);
    const float4* xv = (const float4*)x;

    float4 w0 = Wr[lane], w1 = Wr[lane + 64];
    float4 x0 = xv[lane], x1 = xv[lane + 64];

    float dot = w0.x * x0.x + w0.y * x0.y + w0.z * x0.z + w0.w * x0.w
              + w1.x * x1.x + w1.y * x1.y + w1.z * x1.z + w1.w * x1.w;
    dot = wave_sum(dot);

    if (lane == 0) {
        float v = dot + b[r];
        if (SILU) v = v / (1.0f + expf(-v));     // silu = x*sigmoid(x)
        y[r] = v;
    }
}

// ---------------- Kernel 1c: LayerNorm + l2-normalize -> qn[512] -----------
__global__ __launch_bounds__(512) void ln_l2norm(
        const float* __restrict__ h, const float* __restrict__ gamma,
        const float* __restrict__ beta, float* __restrict__ qn) {
    __shared__ float s1[8], s2[8];
    const int t = threadIdx.x;                   // 512 threads = 8 waves
    const int wid = t >> 6, lane = t & 63;

    float x = h[t];
    float a = x, bb = x * x;
#pragma unroll
    for (int s = 32; s > 0; s >>= 1) { a += __shfl_xor(a, s); bb += __shfl_xor(bb, s); }
    if (lane == 0) { s1[wid] = a; s2[wid] = bb; }
    __syncthreads();

    float suma = 0.f, sumb = 0.f;
#pragma unroll
    for (int i = 0; i < 8; ++i) { suma += s1[i]; sumb += s2[i]; }
    float mu  = suma * (1.0f / KEY_DIM);
    float var = sumb * (1.0f / KEY_DIM) - mu * mu;      // biased, like torch LN
    float ln  = (x - mu) / sqrtf(var + 1e-5f) * gamma[t] + beta[t];

    float c = wave_sum(ln * ln);
    __syncthreads();
    if (lane == 0) s1[wid] = c;
    __syncthreads();
    float ss = 0.f;
#pragma unroll
    for (int i = 0; i < 8; ++i) ss += s1[i];
    float n = fmaxf(sqrtf(ss), 1e-12f);
    qn[t] = ln / n;
}

// ---------------- Kernel 2: cosine sim + per-block top-16 ------------------
// Software pipeline with UNCONDITIONAL prefetch (counted vmcnt): uniform 61
// tiles of 2 rows per wave; pair-unrolled loop with named buffers A/B so the
// compiler emits s_waitcnt vmcnt(4) instead of vmcnt(0). Tail peeled outside.
// Half-packed butterfly: stage 32 per row, pack rows into lane halves,
// stages 16..1 once, one sqrt/div, 2 broadcasts.

__device__ __forceinline__ void load2(const float* __restrict__ keys, int base, int lane,
                                      float4& a0, float4& a1, float4& b0, float4& b1) {
    const float4* k0 = (const float4*)(keys + (size_t)base * KEY_DIM);
    const float4* k1 = (const float4*)(keys + (size_t)(base + 1) * KEY_DIM);
    a0 = k0[lane]; a1 = k0[lane + 64];
    b0 = k1[lane]; b1 = k1[lane + 64];
}

__device__ __forceinline__ void process2(const float4& a0, const float4& a1,
                                         const float4& b0, const float4& b1,
                                         float4 q0, float4 q1, int base, int lane,
                                         float (&v)[16], int (&id)[16]) {
    float d0 = a0.x * q0.x + a0.y * q0.y + a0.z * q0.z + a0.w * q0.w
             + a1.x * q1.x + a1.y * q1.y + a1.z * q1.z + a1.w * q1.w;
    float s0 = a0.x * a0.x + a0.y * a0.y + a0.z * a0.z + a0.w * a0.w
             + a1.x * a1.x + a1.y * a1.y + a1.z * a1.z + a1.w * a1.w;
    float d1 = b0.x * q0.x + b0.y * q0.y + b0.z * q0.z + b0.w * q0.w
             + b1.x * q1.x + b1.y * q1.y + b1.z * q1.z + b1.w * q1.w;
    float s1 = b0.x * b0.x + b0.y * b0.y + b0.z * b0.z + b0.w * b0.w
             + b1.x * b1.x + b1.y * b1.y + b1.z * b1.z + b1.w * b1.w;

    // stage 32 per row
    d0 += __shfl_xor(d0, 32); s0 += __shfl_xor(s0, 32);
    d1 += __shfl_xor(d1, 32); s1 += __shfl_xor(s1, 32);

    // pack: low half of lanes takes row0's partials, high half row1's
    const bool hi = (lane >= 32);
    float pd = hi ? d1 : d0;
    float ps = hi ? s1 : s0;
#pragma unroll
    for (int s = 16; s > 0; s >>= 1) {           // stays within each half
        pd += __shfl_xor(pd, s);
        ps += __shfl_xor(ps, s);
    }
    float simp = pd / fmaxf(sqrtf(ps), 1e-12f);
    float sim0 = __shfl(simp, 0);
    float sim1 = __shfl(simp, 32);

#pragma unroll
    for (int j = 0; j < 2; ++j) {
        float sim = j ? sim1 : sim0;
        if (sim > v[15]) {                       // wave-uniform branch
            float cv = sim; int ci = base + j;
#pragma unroll
            for (int jj = 0; jj < 16; ++jj) {
                if (cv > v[jj]) {
                    float tv = v[jj]; int ti = id[jj];
                    v[jj] = cv; id[jj] = ci; cv = tv; ci = ti;
                }
            }
        }
    }
}

__global__ __launch_bounds__(256) void sim_topk(
        const float* __restrict__ keys, const float* __restrict__ qn,
        float* __restrict__ cand_v, int* __restrict__ cand_i) {
    const int wid  = threadIdx.x >> 6;
    const int lane = threadIdx.x & 63;
    const int gw   = blockIdx.x * 4 + wid;        // 0..4095

    const float4* q = (const float4*)qn;
    float4 q0 = q[lane], q1 = q[lane + 64];

    float v[16]; int id[16];
#pragma unroll
    for (int j = 0; j < 16; ++j) { v[j] = -FLT_MAX; id[j] = 0x7fffffff; }

    float4 Aa0, Aa1, Ab0, Ab1;                    // buffer A (tile even)
    float4 Ba0, Ba1, Bb0, Bb1;                    // buffer B (tile odd)

    int base = gw * 2;
    load2(keys, base, lane, Aa0, Aa1, Ab0, Ab1);  // tile 0

    // steady state: 30 pairs -> processes tiles 0..59, prefetches up to tile 60
#pragma unroll 1
    for (int p = 0; p < (NTILES - 1) / 2; ++p) {
        load2(keys, base + TSTRIDE, lane, Ba0, Ba1, Bb0, Bb1);          // t+1
        process2(Aa0, Aa1, Ab0, Ab1, q0, q1, base, lane, v, id);        // t
        load2(keys, base + 2 * TSTRIDE, lane, Aa0, Aa1, Ab0, Ab1);      // t+2
        process2(Ba0, Ba1, Bb0, Bb1, q0, q1, base + TSTRIDE, lane, v, id); // t+1
        base += 2 * TSTRIDE;
    }
    process2(Aa0, Aa1, Ab0, Ab1, q0, q1, base, lane, v, id);            // tile 60

    // tail: 288 rows, waves 0..143 take one extra tile (vmcnt(0) here is fine)
    if (gw * 2 < TAILROWS) {
        load2(keys, base + TSTRIDE, lane, Ba0, Ba1, Bb0, Bb1);
        process2(Ba0, Ba1, Bb0, Bb1, q0, q1, base + TSTRIDE, lane, v, id);
    }

    // merge 4 waves' top-16 -> block top-16
    __shared__ float bv[64];
    __shared__ int   bi[64];
    if (lane == 0) {
#pragma unroll
        for (int j = 0; j < 16; ++j) { bv[wid * 16 + j] = v[j]; bi[wid * 16 + j] = id[j]; }
    }
    __syncthreads();
    if (wid == 0) {
        float lv = bv[lane]; int li = bi[lane];
        for (int rr = 0; rr < NRET; ++rr) {
            float mv = lv; int mi = li;
#pragma unroll
            for (int s = 32; s > 0; s >>= 1) {
                float ov = __shfl_xor(mv, s); int oi = __shfl_xor(mi, s);
                if (ov > mv || (ov == mv && oi < mi)) { mv = ov; mi = oi; }
            }
            if (lane == 0) {
                cand_v[blockIdx.x * NRET + rr] = mv;
                cand_i[blockIdx.x * NRET + rr] = mi;
            }
            if (lv == mv && li == mi) { lv = -FLT_MAX; li = 0x7fffffff; }  // pop winner
        }
    }
}

// ---------------- Kernel 3: global top-16 + softmax + gather ---------------
__global__ __launch_bounds__(256) void merge_out(
        const float* __restrict__ cand_v, const int* __restrict__ cand_i,
        const float* __restrict__ values, float* __restrict__ out) {
    const int tid  = threadIdx.x;
    const int wid  = tid >> 6;
    const int lane = tid & 63;
    const int M4 = (NBLK2 * NRET) / 4;           // 4096 float4 groups

    float v[16]; int id[16];
#pragma unroll
    for (int j = 0; j < 16; ++j) { v[j] = -FLT_MAX; id[j] = 0x7fffffff; }

    const float4* cv4 = (const float4*)cand_v;
    const int4*   ci4 = (const int4*)cand_i;
    for (int c = tid; c < M4; c += 256) {        // 16 iterations, vector loads
        float4 cv = cv4[c]; int4 ci = ci4[c];
        float cvs[4] = {cv.x, cv.y, cv.z, cv.w};
        int   cis[4] = {ci.x, ci.y, ci.z, ci.w};
#pragma unroll
        for (int u = 0; u < 4; ++u) {
            float cu = cvs[u]; int iu = cis[u];
            if (cu > v[15]) {
#pragma unroll
                for (int j = 0; j < 16; ++j) {
                    if (cu > v[j]) {
                        float tv = v[j]; int ti = id[j];
                        v[j] = cu; id[j] = iu; cu = tv; iu = ti;
                    }
                }
            }
        }
    }

    // per-wave argmax-pop of 16 winners -> LDS
    __shared__ float sv[64];
    __shared__ int   si[64];
    for (int rr = 0; rr < NRET; ++rr) {
        float mv = v[0]; int mi = id[0];
#pragma unroll
        for (int s = 32; s > 0; s >>= 1) {
            float ov = __shfl_xor(mv, s); int oi = __shfl_xor(mi, s);
            if (ov > mv || (ov == mv && oi < mi)) { mv = ov; mi = oi; }
        }
        if (v[0] == mv && id[0] == mi) {         // unique winner (unique indices)
#pragma unroll
            for (int j = 0; j < 15; ++j) { v[j] = v[j + 1]; id[j] = id[j + 1]; }
            v[15] = -FLT_MAX; id[15] = 0x7fffffff;
        }
        if (lane == 0) { sv[wid * 16 + rr] = mv; si[wid * 16 + rr] = mi; }
    }
    __syncthreads();

    if (wid == 0) {
        float lv = sv[lane]; int li = si[lane];
        float sel_v = -FLT_MAX; int sel_i = 0;
        for (int rr = 0; rr < NRET; ++rr) {
            float mv = lv; int mi = li;
#pragma unroll
            for (int s = 32; s > 0; s >>= 1) {
                float ov = __shfl_xor(mv, s); int oi = __shfl_xor(mi, s);
                if (ov > mv || (ov == mv && oi < mi)) { mv = ov; mi = oi; }
            }
            if (lv == mv && li == mi) { lv = -FLT_MAX; li = 0x7fffffff; }
            if (lane == rr) { sel_v = mv; sel_i = mi; }
        }

        // softmax over the 16 (lane 0 holds the max: rounds are descending)
        float m0 = __shfl(sel_v, 0);
        float e = (lane < NRET) ? expf(sel_v - m0) : 0.0f;
        float denom = wave_sum(e);

        float acc0 = 0.f, acc1 = 0.f;
        for (int rr = 0; rr < NRET; ++rr) {
            float ar = __shfl(e, rr) / denom;
            int   ir = __shfl(sel_i, rr);
            const float* vr = values + (size_t)ir * VALUE_DIM;
            acc0 += ar * vr[lane];
            acc1 += ar * vr[lane + 64];
        }
        out[lane]      = acc0;
        out[lane + 64] = acc1;
    }
}

extern "C" void kernel_launch(void* const* d_in, const int* in_sizes, int n_in,
                              void* d_out, int out_size, void* d_ws, size_t ws_size,
                              hipStream_t stream) {
    const float* query  = (const float*)d_in[0];
    const float* W1     = (const float*)d_in[1];
    const float* b1     = (const float*)d_in[2];
    const float* W2     = (const float*)d_in[3];
    const float* b2     = (const float*)d_in[4];
    const float* gamma  = (const float*)d_in[5];
    const float* beta   = (const float*)d_in[6];
    const float* keys   = (const float*)d_in[7];
    const float* values = (const float*)d_in[8];
    float* out = (float*)d_out;

    float* ws = (float*)d_ws;
    float* h1     = ws;                  // 512
    float* h2     = ws + 512;            // 512
    float* qn     = ws + 1024;           // 512
    float* cand_v = ws + 2048;           // NBLK2*16 floats (16 KB-aligned)
    int*   cand_i = (int*)(ws + 2048 + NBLK2 * NRET);

    matvec512<true ><<<128, 256, 0, stream>>>(W1, query, b1, h1);
    matvec512<false><<<128, 256, 0, stream>>>(W2, h1, b2, h2);
    ln_l2norm<<<1, 512, 0, stream>>>(h2, gamma, beta, qn);
    sim_topk<<<NBLK2, 256, 0, stream>>>(keys, qn, cand_v, cand_i);
    merge_out<<<1, 256, 0, stream>>>(cand_v, cand_i, values, out);
}